// Round 8
// baseline (44.596 us; speedup 1.0000x reference)
//
#include <hip/hip_runtime.h>
#include <cstdint>
#include <cfloat>
#include <cstddef>

#define BB 8
#define VV 2048
#define SS 4
#define FF 64
#define KK 8

// Largest f32 that stays FINITE when rounded to bf16 (FLT_MAX -> bf16 = +inf).
#define BF16_SAFE_MAX 3.3e38f

typedef unsigned long long u64;

static __forceinline__ __device__ u64 shfl_xor_u64(u64 x, int m) {
    int lo = __shfl_xor((int)(unsigned)x, m, 64);
    int hi = __shfl_xor((int)(unsigned)(x >> 32), m, 64);
    return ((u64)(unsigned)hi << 32) | (unsigned)lo;
}

#define CEK(A, x, y) { u64 lo_ = A[x] < A[y] ? A[x] : A[y];                    \
                       u64 hi_ = A[x] < A[y] ? A[y] : A[x];                    \
                       A[x] = lo_; A[y] = hi_; }

// Batcher odd-even mergesort, n=8, 19 comparators
#define SORT8(K)                                                               \
    CEK(K,0,1) CEK(K,2,3) CEK(K,4,5) CEK(K,6,7)                                \
    CEK(K,0,2) CEK(K,1,3) CEK(K,4,6) CEK(K,5,7)                                \
    CEK(K,1,2) CEK(K,5,6)                                                      \
    CEK(K,0,4) CEK(K,1,5) CEK(K,2,6) CEK(K,3,7)                                \
    CEK(K,2,4) CEK(K,3,5)                                                      \
    CEK(K,1,2) CEK(K,3,4) CEK(K,5,6)

// 32 lanes per row, 2 rows per wave, 8 strided rows per block.
// Two-pass LDS staging (20 KB) -> 6 blocks/CU.
__global__ __launch_bounds__(256, 6)
void knn_topk_kernel(const float* __restrict__ coords,   // [B,V,S] f32
                     const float* __restrict__ feats,    // [B,V,F] f32
                     const float* __restrict__ active,   // [B,1]   f32
                     float* __restrict__ out_dist,       // [B,V,K-1]
                     float* __restrict__ out_feat)       // [B,V,K-1,F]
{
#pragma clang fp contract(off)
    __shared__ float4 sc[VV / 2];   // 16 KB
    __shared__ float  sn[VV / 2];   //  4 KB

    const int b     = blockIdx.y;
    const int tid   = threadIdx.x;
    const int l     = tid & 31;            // lane within 32-lane row-group
    const int j     = tid >> 5;            // row slot 0..7
    const int v     = blockIdx.x + (j << 8);
    const int gbase = tid & 32;            // group base within the wave (0 or 32)

    const float A = active[b];
    int Ai = (int)ceilf(A);
    Ai = Ai < 0 ? 0 : (Ai > VV ? VV : Ai);

    const size_t row = (size_t)b * VV + v;
    const float4* cg = reinterpret_cast<const float4*>(coords + (size_t)b * VV * SS);

    const bool rowActive = ((float)v < A);
    const bool heavy = (__ballot(rowActive) != 0ULL);   // wave-uniform

    const float4 cv = cg[v];
    float qp0 = cv.x * cv.x, qp1 = cv.y * cv.y, qp2 = cv.z * cv.z, qp3 = cv.w * cv.w;
    const float nv = ((qp0 + qp1) + qp2) + qp3;

    const int nt = (Ai + 31) >> 5;          // total candidate tiles (32 wide)

    u64   top[KK];
    float tau = 0.0f;

#define STAGE(P)                                                               \
    for (int i = tid; i < VV / 2; i += 256) {                                  \
        const float4 c = cg[i + ((P) << 10)];                                  \
        sc[i] = c;                                                             \
        float p0 = c.x * c.x, p1 = c.y * c.y, p2 = c.z * c.z, p3 = c.w * c.w;  \
        sn[i] = ((p0 + p1) + p2) + p3;                                         \
    }

#define DIST_SD(WI)                                                            \
    const float4 cw = sc[(WI)];                                                \
    const float  nw = sn[(WI)];                                                \
    float p0 = cv.x * cw.x, p1 = cv.y * cw.y,                                  \
          p2 = cv.z * cw.z, p3 = cv.w * cw.w;                                  \
    float dot = ((p0 + p1) + p2) + p3;                                         \
    float sd = -2.0f * dot;                                                    \
    sd = sd + nv;                                                              \
    sd = sd + nw;                                                              \
    sd = fabsf(sd);

// tau-filtered scan: selection work only on ballot hits (rare)
#define HIT_SCAN(T0, T1)                                                       \
    for (int t = (T0); t < (T1); ++t) {                                        \
        const int w  = (t << 5) + l;                                           \
        const int wi = w & (VV / 2 - 1);                                       \
        DIST_SD(wi)                                                            \
        const bool pred = rowActive && ((float)w < A) && (sd < tau);           \
        const u64 ball = __ballot(pred);                                       \
        unsigned hits = (unsigned)(ball >> gbase);                             \
        while (hits) {                                                         \
            const int s = __builtin_ctz(hits);                                 \
            hits &= hits - 1;                                                  \
            const unsigned sdb =                                               \
                (unsigned)__shfl((int)__float_as_uint(sd), gbase + s, 64);     \
            const u64 k = ((u64)sdb << 32) | (unsigned)((t << 5) + s);         \
            if (k < top[KK - 1]) {      /* uniform within group */             \
                top[KK - 1] = k;                                               \
                _Pragma("unroll")                                              \
                for (int i = KK - 1; i > 0; --i) {                             \
                    u64 a0 = top[i - 1], b0 = top[i];                          \
                    top[i - 1] = a0 < b0 ? a0 : b0;                            \
                    top[i]     = a0 < b0 ? b0 : a0;                            \
                }                                                              \
                tau = __uint_as_float((unsigned)(top[KK - 1] >> 32));          \
            }                                                                  \
        }                                                                      \
    }

    // ---- pass 1 staging: w in [0, 1024) ----
    STAGE(0)
    __syncthreads();

    if (heavy) {
        // ---- phase 1: tiles 0..7 (w < 256), exact top-8 of the prefix ----
        u64 bk[KK];
#pragma unroll
        for (int k = 0; k < 8; ++k) {
            const int w = (k << 5) + l;
            DIST_SD(w)
            const bool m = rowActive && ((float)w < A);
            const float dvf = m ? sd : FLT_MAX;
            bk[k] = ((u64)__float_as_uint(dvf) << 32) | (unsigned)w;
        }
        SORT8(bk)
#pragma unroll
        for (int i = 0; i < KK; ++i) top[i] = bk[i];

        // 5-level truncated bitonic merge within the 32-lane group
#pragma unroll
        for (int step = 1; step < 32; step <<= 1) {
            u64 t[KK];
#pragma unroll
            for (int i = 0; i < KK; ++i) {
                u64 pb = shfl_xor_u64(top[KK - 1 - i], step);
                u64 a0 = top[i];
                t[i] = a0 < pb ? a0 : pb;
            }
            CEK(t,0,4) CEK(t,1,5) CEK(t,2,6) CEK(t,3,7)
            CEK(t,0,2) CEK(t,1,3) CEK(t,4,6) CEK(t,5,7)
            CEK(t,0,1) CEK(t,2,3) CEK(t,4,5) CEK(t,6,7)
#pragma unroll
            for (int i = 0; i < KK; ++i) top[i] = t[i];
        }
        tau = __uint_as_float((unsigned)(top[KK - 1] >> 32));

        // ---- phase 2a: tiles 8..min(nt,32) in window 0 ----
        const int t1 = nt < 32 ? nt : 32;
        HIT_SCAN(8, t1)
    }

    // ---- pass 2 staging: w in [1024, 2048) ----
    if (nt > 32) {
        __syncthreads();
        STAGE(1)
        __syncthreads();
        if (heavy) {
            HIT_SCAN(32, nt)
        }
    }
#undef STAGE
#undef DIST_SD
#undef HIT_SCAN

    // ---- trivial rows: top-8 of all-FLT_MAX row = indices 0..7 ----
    if (!heavy) {
        if (l >= 1 && l < KK)
            out_dist[row * (KK - 1) + (l - 1)] = BF16_SAFE_MAX;
#pragma unroll
        for (int r = 1; r < KK; ++r) {
            const float2 val = reinterpret_cast<const float2*>(
                feats + ((size_t)b * VV + r) * FF)[l];
            reinterpret_cast<float2*>(out_feat + (row * (KK - 1) + (r - 1)) * FF)[l] = val;
        }
        return;
    }

    // ---- epilogue: all 32 lanes hold the row's top-8; rank 0 = self ----
    unsigned kk = 0;
#pragma unroll
    for (int r = 1; r < KK; ++r) kk = (l == r) ? (unsigned)(top[r] >> 32) : kk;
    if (l >= 1 && l < KK) {
        float d = __uint_as_float(kk);
        if (!(d <= BF16_SAFE_MAX)) d = BF16_SAFE_MAX;  // finite in bf16; kills NaN
        out_dist[row * (KK - 1) + (l - 1)] = d;
    }

#pragma unroll
    for (int r = 1; r < KK; ++r) {
        const unsigned idx = (unsigned)top[r] & (VV - 1);
        const float2 val = reinterpret_cast<const float2*>(
            feats + ((size_t)b * VV + idx) * FF)[l];
        reinterpret_cast<float2*>(out_feat + (row * (KK - 1) + (r - 1)) * FF)[l] = val;
    }
}

extern "C" void kernel_launch(void* const* d_in, const int* in_sizes, int n_in,
                              void* d_out, int out_size, void* d_ws, size_t ws_size,
                              hipStream_t stream)
{
    const float* coords = (const float*)d_in[0];
    const float* feats  = (const float*)d_in[1];
    const float* act    = (const float*)d_in[2];
    float* out_dist = (float*)d_out;
    float* out_feat = out_dist + (size_t)BB * VV * (KK - 1);

    dim3 grid(VV / 8, BB);    // 256 x 8 blocks, 8 strided rows each
    knn_topk_kernel<<<grid, dim3(256), 0, stream>>>(coords, feats, act,
                                                    out_dist, out_feat);
}

// Round 9
// 38.294 us; speedup vs baseline: 1.1646x; 1.1646x over previous
//
#include <hip/hip_runtime.h>
#include <cstdint>
#include <cfloat>
#include <cstddef>

#define BB 8
#define VV 2048
#define SS 4
#define FF 64
#define KK 8

// Largest f32 that stays FINITE when rounded to bf16 (FLT_MAX -> bf16 = +inf).
#define BF16_SAFE_MAX 3.3e38f

typedef unsigned long long u64;

static __forceinline__ __device__ u64 shfl_xor_u64(u64 x, int m) {
    int lo = __shfl_xor((int)(unsigned)x, m, 64);
    int hi = __shfl_xor((int)(unsigned)(x >> 32), m, 64);
    return ((u64)(unsigned)hi << 32) | (unsigned)lo;
}

#define CEK(A, x, y) { u64 lo_ = A[x] < A[y] ? A[x] : A[y];                    \
                       u64 hi_ = A[x] < A[y] ? A[y] : A[x];                    \
                       A[x] = lo_; A[y] = hi_; }

// Batcher odd-even mergesort, n=8, 19 comparators (high ILP)
#define SORT8(K)                                                               \
    CEK(K,0,1) CEK(K,2,3) CEK(K,4,5) CEK(K,6,7)                                \
    CEK(K,0,2) CEK(K,1,3) CEK(K,4,6) CEK(K,5,7)                                \
    CEK(K,1,2) CEK(K,5,6)                                                      \
    CEK(K,0,4) CEK(K,1,5) CEK(K,2,6) CEK(K,3,7)                                \
    CEK(K,2,4) CEK(K,3,5)                                                      \
    CEK(K,1,2) CEK(K,3,4) CEK(K,5,6)

// merge sorted-asc T(8) with sorted-asc Bk(8): keep 8 smallest, sorted, in T
#define MERGE8(T, Bk) {                                                        \
    u64 t[KK];                                                                 \
    t[0] = T[0] < Bk[7] ? T[0] : Bk[7];                                        \
    t[1] = T[1] < Bk[6] ? T[1] : Bk[6];                                        \
    t[2] = T[2] < Bk[5] ? T[2] : Bk[5];                                        \
    t[3] = T[3] < Bk[4] ? T[3] : Bk[4];                                        \
    t[4] = T[4] < Bk[3] ? T[4] : Bk[3];                                        \
    t[5] = T[5] < Bk[2] ? T[5] : Bk[2];                                        \
    t[6] = T[6] < Bk[1] ? T[6] : Bk[1];                                        \
    t[7] = T[7] < Bk[0] ? T[7] : Bk[0];                                        \
    CEK(t,0,4) CEK(t,1,5) CEK(t,2,6) CEK(t,3,7)                                \
    CEK(t,0,2) CEK(t,1,3) CEK(t,4,6) CEK(t,5,7)                                \
    CEK(t,0,1) CEK(t,2,3) CEK(t,4,5) CEK(t,6,7)                                \
    T[0]=t[0]; T[1]=t[1]; T[2]=t[2]; T[3]=t[3];                                \
    T[4]=t[4]; T[5]=t[5]; T[6]=t[6]; T[7]=t[7]; }

// 32 lanes per query row, 2 rows per wave, 8 strided rows per block.
// LDS 20480 B = 160KB/8 exactly; VGPR<=64 -> 8 blocks/CU.
// grid = 2048 = 256 CU x 8 -> single dispatch round, zero tail.
__global__ __launch_bounds__(256, 8)
void knn_topk_kernel(const float* __restrict__ coords,   // [B,V,S] f32
                     const float* __restrict__ feats,    // [B,V,F] f32
                     const float* __restrict__ active,   // [B,1]   f32
                     float* __restrict__ out_dist,       // [B,V,K-1]
                     float* __restrict__ out_feat)       // [B,V,K-1,F]
{
#pragma clang fp contract(off)
    __shared__ float4 sc[VV / 2];   // 16 KB (one half-range of candidates)
    __shared__ float  sn[VV / 2];   //  4 KB

    const int b   = blockIdx.y;
    const int tid = threadIdx.x;
    const int l   = tid & 31;              // lane within 32-lane row-group
    const int j   = tid >> 5;              // row slot 0..7
    const int v   = blockIdx.x + (j << 8); // strided rows: perfect balance

    const float A = active[b];
    int Ai = (int)ceilf(A);
    Ai = Ai < 0 ? 0 : (Ai > VV ? VV : Ai);

    const size_t row = (size_t)b * VV + v;
    const float4* cg = reinterpret_cast<const float4*>(coords + (size_t)b * VV * SS);

    const bool rowActive = ((float)v < A);
    const bool heavy = (__ballot(rowActive) != 0ULL);   // wave-uniform

    // query coords/norm from global (row may live in either staging pass)
    const float4 cv = cg[v];
    float qp0 = cv.x * cv.x, qp1 = cv.y * cv.y, qp2 = cv.z * cv.z, qp3 = cv.w * cv.w;
    const float nv = ((qp0 + qp1) + qp2) + qp3;

    // running top-8, sorted ascending (u64 key = dist_bits<<32 | w)
    u64 top[KK];
#pragma unroll
    for (int i = 0; i < KK; ++i) top[i] = ~0ULL;

    const int nfullt      = Ai >> 5;                         // tiles fully < A
    int ntiles_total      = (Ai + 31) >> 5;
    if (ntiles_total < KK) ntiles_total = KK;                // >=8 real keys/lane
    const int nb_total    = (ntiles_total + 7) >> 3;         // batches (8 tiles each)
    const int nb1         = nb_total < 4 ? nb_total : 4;     // pass-1 batches

#define STAGE(P)                                                               \
    for (int i = tid; i < VV / 2; i += 256) {                                  \
        const float4 c = cg[i + ((P) << 10)];                                  \
        sc[i] = c;                                                             \
        float p0 = c.x * c.x, p1 = c.y * c.y, p2 = c.z * c.z, p3 = c.w * c.w;  \
        sn[i] = ((p0 + p1) + p2) + p3;                                         \
    }

#define SCAN_BATCH(M)                                                          \
    {                                                                          \
        const int bt = (M) << 3;                                               \
        u64 bk[KK];                                                            \
        if (bt + 8 <= nfullt) {                                                \
            _Pragma("unroll")                                                  \
            for (int k = 0; k < 8; ++k) {                                      \
                const int w  = ((bt + k) << 5) + l;                            \
                const int wi = w & (VV / 2 - 1);                               \
                const float4 cw = sc[wi];                                      \
                const float  nw = sn[wi];                                      \
                float p0 = cv.x * cw.x, p1 = cv.y * cw.y,                      \
                      p2 = cv.z * cw.z, p3 = cv.w * cw.w;                      \
                float dot = ((p0 + p1) + p2) + p3;                             \
                float sd = -2.0f * dot;                                        \
                sd = sd + nv;                                                  \
                sd = sd + nw;                                                  \
                sd = fabsf(sd);                                                \
                const float dvf = rowActive ? sd : FLT_MAX;                    \
                bk[k] = ((u64)__float_as_uint(dvf) << 32) | (unsigned)w;       \
            }                                                                  \
        } else {                                                               \
            _Pragma("unroll")                                                  \
            for (int k = 0; k < 8; ++k) {                                      \
                const int w  = ((bt + k) << 5) + l;                            \
                const int wi = w & (VV / 2 - 1);                               \
                const float4 cw = sc[wi];                                      \
                const float  nw = sn[wi];                                      \
                float p0 = cv.x * cw.x, p1 = cv.y * cw.y,                      \
                      p2 = cv.z * cw.z, p3 = cv.w * cw.w;                      \
                float dot = ((p0 + p1) + p2) + p3;                             \
                float sd = -2.0f * dot;                                        \
                sd = sd + nv;                                                  \
                sd = sd + nw;                                                  \
                sd = fabsf(sd);                                                \
                const bool m = rowActive && ((float)w < A);                    \
                const float dvf = m ? sd : FLT_MAX;                            \
                bk[k] = ((u64)__float_as_uint(dvf) << 32) | (unsigned)w;       \
            }                                                                  \
        }                                                                      \
        SORT8(bk)                                                              \
        MERGE8(top, bk)                                                        \
    }

    // ---- pass 1: candidates w in [0, 1024) ----
    STAGE(0)
    __syncthreads();
    if (heavy) {
        for (int m = 0; m < nb1; ++m) SCAN_BATCH(m)
    }

    // ---- pass 2: candidates w in [1024, 2048) ----
    if (nb_total > 4) {
        __syncthreads();          // everyone done reading pass-1 LDS
        STAGE(1)
        __syncthreads();
        if (heavy) {
            for (int m = 4; m < nb_total; ++m) SCAN_BATCH(m)
        }
    }
#undef STAGE
#undef SCAN_BATCH

    // ---- trivial rows: top-8 of all-FLT_MAX row = indices 0..7 ----
    if (!heavy) {
        if (l >= 1 && l < KK)
            out_dist[row * (KK - 1) + (l - 1)] = BF16_SAFE_MAX;
#pragma unroll
        for (int r = 1; r < KK; ++r) {
            const float2 val = reinterpret_cast<const float2*>(
                feats + ((size_t)b * VV + r) * FF)[l];
            reinterpret_cast<float2*>(out_feat + (row * (KK - 1) + (r - 1)) * FF)[l] = val;
        }
        return;
    }

    // ---- 5-level truncated bitonic merge across the 32-lane group ----
#pragma unroll
    for (int step = 1; step < 32; step <<= 1) {
        u64 t[KK];
#pragma unroll
        for (int i = 0; i < KK; ++i) {
            u64 pb = shfl_xor_u64(top[KK - 1 - i], step);
            u64 a0 = top[i];
            t[i] = a0 < pb ? a0 : pb;
        }
        CEK(t,0,4) CEK(t,1,5) CEK(t,2,6) CEK(t,3,7)
        CEK(t,0,2) CEK(t,1,3) CEK(t,4,6) CEK(t,5,7)
        CEK(t,0,1) CEK(t,2,3) CEK(t,4,5) CEK(t,6,7)
#pragma unroll
        for (int i = 0; i < KK; ++i) top[i] = t[i];
    }
    // all 32 lanes hold the row's top-8 ascending; rank 0 = self/dropped

    // ---- epilogue ----
    unsigned kk = 0;
#pragma unroll
    for (int r = 1; r < KK; ++r) kk = (l == r) ? (unsigned)(top[r] >> 32) : kk;
    if (l >= 1 && l < KK) {
        float d = __uint_as_float(kk);
        if (!(d <= BF16_SAFE_MAX)) d = BF16_SAFE_MAX;  // finite in bf16; kills NaN
        out_dist[row * (KK - 1) + (l - 1)] = d;
    }

#pragma unroll
    for (int r = 1; r < KK; ++r) {
        const unsigned idx = (unsigned)top[r] & (VV - 1);
        const float2 val = reinterpret_cast<const float2*>(
            feats + ((size_t)b * VV + idx) * FF)[l];
        reinterpret_cast<float2*>(out_feat + (row * (KK - 1) + (r - 1)) * FF)[l] = val;
    }
}

extern "C" void kernel_launch(void* const* d_in, const int* in_sizes, int n_in,
                              void* d_out, int out_size, void* d_ws, size_t ws_size,
                              hipStream_t stream)
{
    const float* coords = (const float*)d_in[0];
    const float* feats  = (const float*)d_in[1];
    const float* act    = (const float*)d_in[2];
    float* out_dist = (float*)d_out;
    float* out_feat = out_dist + (size_t)BB * VV * (KK - 1);

    dim3 grid(VV / 8, BB);    // 2048 blocks = 256 CU x 8 blocks/CU: one round
    knn_topk_kernel<<<grid, dim3(256), 0, stream>>>(coords, feats, act,
                                                    out_dist, out_feat);
}